// Round 4
// baseline (106.678 us; speedup 1.0000x reference)
//
#include <hip/hip_runtime.h>
#include <math.h>

#define NV 512
#define KC 32
#define NB 192
#define LOG2PI 1.8378770664093453f

typedef __attribute__((ext_vector_type(8))) short short8;
typedef __attribute__((ext_vector_type(4))) float float4v;
typedef __attribute__((ext_vector_type(4))) int int4v;

// ws layout (floats) — all per-block EXCLUSIVE slices, fully overwritten
// every launch (0xAA poison harmless):
//   WS_GS: 96 gemm slices, stride 592: [smpart 16x32][v 64][mm 1]
//   WS_ST: 12 stat slices, stride 580: [u 512][sx1 32][sx2 32][xx 1]
//   WS_P : [coef 32][logdet 1]
#define WS_GS 0
#define GS_STRIDE 592
#define WS_ST 56832
#define ST_STRIDE 580
#define WS_P 63792

// pack two fp32 (as uint bits) into two bf16 with round-half-up
static __device__ inline uint pkbf(uint lo, uint hi) {
    return ((hi + 0x8000u) & 0xffff0000u) | ((lo + 0x8000u) >> 16);
}

__global__ __launch_bounds__(256) void mega_kernel(
    const float* __restrict__ X, const float* __restrict__ C,
    const float* __restrict__ G, const float* __restrict__ W,
    const float* __restrict__ bias, const float* __restrict__ sigma,
    const float* __restrict__ rho, float* __restrict__ wsF)
{
    const int bid = blockIdx.x, tid = threadIdx.x;
    const int blk_b = bid >> 3, blk_i = bid & 7;   // 12 b-tiles x 8 i-tiles
    const int b0 = blk_b * 16, i0blk = blk_i * 64;
    const int w = tid >> 6, lane = tid & 63;
    const int m = lane & 15, q = lane >> 4;
    const int i0w = i0blk + w * 16;

    __shared__ int asg[NV];
    __shared__ float Gs[KC * KC];
    __shared__ uint Gbits[KC];
    __shared__ unsigned long long kmask[KC][8];  // [c1][g]: bit j = G[c1][asg[g*64+j]]
    __shared__ float smL[16 * KC];
    __shared__ float varr[64];
    __shared__ float mmred[4];
    __shared__ float smrows[16][KC];
    __shared__ int cnt[KC];
    __shared__ float ldred[KC];

    // ---- cluster assignment from one-hot C (exact 0/1), float4 loads
    {
        const int n0 = tid * 2;
        #pragma unroll
        for (int h = 0; h < 2; ++h) {
            const int n = n0 + h;
            const float* row = C + n * KC;
            float a = 0.f;
            #pragma unroll
            for (int c4 = 0; c4 < 8; ++c4) {
                const float4 f = *(const float4*)(row + c4 * 4);
                a += f.x * (float)(c4 * 4) + f.y * (float)(c4 * 4 + 1)
                   + f.z * (float)(c4 * 4 + 2) + f.w * (float)(c4 * 4 + 3);
            }
            asg[n] = (int)(a + 0.5f);
        }
    }
    for (int l = tid; l < KC * KC; l += 256) Gs[l] = G[l];
    for (int l = tid; l < 16 * KC; l += 256) smL[l] = 0.f;
    if (tid < 64) varr[tid] = 0.f;
    __syncthreads();
    if (tid < KC) {
        uint bits = 0;
        #pragma unroll
        for (int c2 = 0; c2 < KC; ++c2)
            bits |= (Gs[tid * KC + c2] > 0.5f ? 1u : 0u) << c2;
        Gbits[tid] = bits;
    }
    __syncthreads();
    // ---- kmask via ballot: wave w covers k-groups 2w, 2w+1
    #pragma unroll
    for (int gi = 0; gi < 2; ++gi) {
        const int g = w * 2 + gi;
        const int a = asg[g * 64 + lane];
        #pragma unroll
        for (int c1 = 0; c1 < KC; ++c1) {
            const unsigned long long bm = __ballot((Gbits[c1] >> a) & 1u);
            if (lane == c1) kmask[c1][g] = bm;
        }
    }
    __syncthreads();

    // ---- MFMA GEMM with in-register fp32->bf16 convert + bitmask masking
    const int carow = asg[i0w + m];
    unsigned long long rm[8];
    #pragma unroll
    for (int g = 0; g < 8; ++g) rm[g] = kmask[carow][g];
    const float* aRow = X + (b0 + m) * NV;
    const float* bRow = W + (i0w + m) * NV;
    const int q8 = q * 8;
    float4v acc = {0.f, 0.f, 0.f, 0.f};
    #pragma unroll
    for (int s = 0; s < 16; ++s) {
        const int k0 = q8 + s * 32;
        const float4 a0 = *(const float4*)(aRow + k0);
        const float4 a1 = *(const float4*)(aRow + k0 + 4);
        const float4 w0 = *(const float4*)(bRow + k0);
        const float4 w1 = *(const float4*)(bRow + k0 + 4);
        const uint bits = (uint)(rm[s >> 1] >> (q8 + ((s & 1) << 5))) & 0xffu;
        const uint b0u = (bits & 1u)   ? __float_as_uint(w0.x) : 0u;
        const uint b1u = (bits & 2u)   ? __float_as_uint(w0.y) : 0u;
        const uint b2u = (bits & 4u)   ? __float_as_uint(w0.z) : 0u;
        const uint b3u = (bits & 8u)   ? __float_as_uint(w0.w) : 0u;
        const uint b4u = (bits & 16u)  ? __float_as_uint(w1.x) : 0u;
        const uint b5u = (bits & 32u)  ? __float_as_uint(w1.y) : 0u;
        const uint b6u = (bits & 64u)  ? __float_as_uint(w1.z) : 0u;
        const uint b7u = (bits & 128u) ? __float_as_uint(w1.w) : 0u;
        int4v ai, bi;
        ai.x = (int)pkbf(__float_as_uint(a0.x), __float_as_uint(a0.y));
        ai.y = (int)pkbf(__float_as_uint(a0.z), __float_as_uint(a0.w));
        ai.z = (int)pkbf(__float_as_uint(a1.x), __float_as_uint(a1.y));
        ai.w = (int)pkbf(__float_as_uint(a1.z), __float_as_uint(a1.w));
        bi.x = (int)pkbf(b0u, b1u);
        bi.y = (int)pkbf(b2u, b3u);
        bi.z = (int)pkbf(b4u, b5u);
        bi.w = (int)pkbf(b6u, b7u);
        acc = __builtin_amdgcn_mfma_f32_16x16x32_bf16(
            __builtin_bit_cast(short8, ai), __builtin_bit_cast(short8, bi), acc, 0, 0, 0);
    }

    // ---- epilogue: C/D layout col=lane&15, row=q*4+reg (m89-verified)
    const int col = i0w + m;
    const float bv = bias[col];
    float vsum = 0.f, mml = 0.f;
    #pragma unroll
    for (int r = 0; r < 4; ++r) {
        const float val = acc[r] + bv;
        vsum += val; mml += val * val;
        atomicAdd(&smL[(q * 4 + r) * KC + carow], val);
    }
    atomicAdd(&varr[w * 16 + m], vsum);
    for (int off = 32; off; off >>= 1) mml += __shfl_down(mml, off, 64);
    if (lane == 0) mmred[w] = mml;
    __syncthreads();
    {
        float* slice = wsF + WS_GS + bid * GS_STRIDE;
        for (int l = tid; l < 16 * KC; l += 256) slice[l] = smL[l];
        if (tid < 64) slice[512 + tid] = varr[tid];
        if (tid == 0) slice[576] = mmred[0] + mmred[1] + mmred[2] + mmred[3];
    }

    // ---- X stats (exact fp32) folded into blk_i==0 blocks, rows [b0,b0+16)
    if (blk_i == 0) {
        __syncthreads();   // mmred consumed above; safe to reuse
        for (int l = tid; l < 16 * KC; l += 256) ((float*)smrows)[l] = 0.f;
        __syncthreads();
        const int c0 = tid * 2;
        const int ca = asg[c0], cb = asg[c0 + 1];
        float u0 = 0.f, u1 = 0.f, xx = 0.f;
        #pragma unroll
        for (int r = 0; r < 16; ++r) {
            const float2 xv = *(const float2*)(X + (b0 + r) * NV + c0);
            u0 += xv.x; u1 += xv.y;
            xx += xv.x * xv.x + xv.y * xv.y;
            atomicAdd(&smrows[r][ca], xv.x);
            atomicAdd(&smrows[r][cb], xv.y);
        }
        for (int off = 32; off; off >>= 1) xx += __shfl_down(xx, off, 64);
        if ((tid & 63) == 0) mmred[tid >> 6] = xx;
        __syncthreads();
        float* st = wsF + WS_ST + blk_b * ST_STRIDE;
        st[c0] = u0; st[c0 + 1] = u1;
        if (tid < KC) {
            float s1 = 0.f, s2 = 0.f;
            #pragma unroll
            for (int r = 0; r < 16; ++r) { const float s = smrows[r][tid]; s1 += s; s2 += s * s; }
            st[512 + tid] = s1;
            st[544 + tid] = s2;
        }
        if (tid == 0) st[576] = mmred[0] + mmred[1] + mmred[2] + mmred[3];
    }

    // ---- coef/logdet in block 0
    if (bid == 0) {
        if (tid < KC) cnt[tid] = 0;
        __syncthreads();
        for (int n = tid; n < NV; n += 256) atomicAdd(&cnt[asg[n]], 1);
        __syncthreads();
        const float s2v = sigma[0] * sigma[0], rh = rho[0];
        const float av = s2v * (1.f - rh), bvv = s2v * rh;
        if (tid < KC) {
            const int nc = cnt[tid];
            wsF[WS_P + tid] = bvv / (av * (av + bvv * (float)nc));
            ldred[tid] = (float)(nc - 1) * logf(av) + logf(av + bvv * (float)nc);
        }
        __syncthreads();
        if (tid == 0) {
            float ld = 0.f;
            for (int c = 0; c < KC; ++c) ld += ldred[c];
            wsF[WS_P + 32] = ld;
        }
    }
}

__global__ __launch_bounds__(512) void finalize_kernel(
    const float* __restrict__ sigma, const float* __restrict__ rho,
    const float* __restrict__ wsF, float* __restrict__ out)
{
    const int tid = threadIdx.x;
    __shared__ float SM1s[KC], SM2s[KC];
    __shared__ float accs[4];   // 0:MM 1:XX 2:cross(u.v) 3:Q
    if (tid < KC) { SM1s[tid] = 0.f; SM2s[tid] = 0.f; }
    if (tid < 4) accs[tid] = 0.f;
    __syncthreads();
    const float* gs = wsF + WS_GS;
    const float* st = wsF + WS_ST;

    // SM1/SM2: thread (c, g) sums rows b = g, g+16, ... over 8 i-slices
    {
        const int c = tid & 31, g = tid >> 5;    // g 0..15
        float s1 = 0.f, s2 = 0.f;
        for (int bb = g; bb < NB; bb += 16) {    // 12 iters
            const float* p = gs + ((bb >> 4) * 8) * GS_STRIDE + (bb & 15) * KC + c;
            float s = 0.f;
            #pragma unroll
            for (int ib = 0; ib < 8; ++ib) s += p[ib * GS_STRIDE];
            s1 += s; s2 += s * s;
        }
        atomicAdd(&SM1s[c], s1);
        atomicAdd(&SM2s[c], s2);
    }
    // u, v, cross (tid == column i, 512 threads == NV)
    {
        float v = 0.f, u = 0.f;
        #pragma unroll
        for (int bb = 0; bb < 12; ++bb)
            v += gs[(bb * 8 + (tid >> 6)) * GS_STRIDE + 512 + (tid & 63)];
        #pragma unroll
        for (int sb = 0; sb < 12; ++sb) u += st[sb * ST_STRIDE + tid];
        float cr = u * v;
        for (int off = 32; off; off >>= 1) cr += __shfl_down(cr, off, 64);
        if ((tid & 63) == 0) atomicAdd(&accs[2], cr);
    }
    // MM
    {
        float mm = (tid < 96) ? gs[tid * GS_STRIDE + 576] : 0.f;
        for (int off = 32; off; off >>= 1) mm += __shfl_down(mm, off, 64);
        if ((tid & 63) == 0) atomicAdd(&accs[0], mm);
    }
    // XX
    {
        float xx = (tid < 12) ? st[tid * ST_STRIDE + 576] : 0.f;
        for (int off = 32; off; off >>= 1) xx += __shfl_down(xx, off, 64);
        if ((tid & 63) == 0) atomicAdd(&accs[1], xx);
    }
    __syncthreads();
    // Q term
    {
        float qv = 0.f;
        if (tid < KC) {
            float s1 = 0.f, s2 = 0.f;
            #pragma unroll
            for (int sb = 0; sb < 12; ++sb) {
                s1 += st[sb * ST_STRIDE + 512 + tid];
                s2 += st[sb * ST_STRIDE + 544 + tid];
            }
            const float coef = wsF[WS_P + tid];
            qv = coef * (s2 * (1.f / NB) + SM2s[tid] * (1.f / NB)
                         - 2.f * s1 * SM1s[tid] * (1.f / ((float)NB * (float)NB)));
        }
        for (int off = 32; off; off >>= 1) qv += __shfl_down(qv, off, 64);
        if (tid == 0) atomicAdd(&accs[3], qv);
    }
    __syncthreads();
    if (tid == 0) {
        const float s2v = sigma[0] * sigma[0], rh = rho[0];
        const float av = s2v * (1.f - rh);
        const float meanD2 = accs[1] * (1.f / NB) + accs[0] * (1.f / NB)
                           - 2.f * accs[2] / ((float)NB * (float)NB);
        const float maha = meanD2 / av - accs[3];
        out[0] = -0.5f * (maha + wsF[WS_P + 32] + (float)NV * LOG2PI);
    }
}

extern "C" void kernel_launch(void* const* d_in, const int* in_sizes, int n_in,
                              void* d_out, int out_size, void* d_ws, size_t ws_size,
                              hipStream_t stream) {
    const float* X     = (const float*)d_in[0];
    const float* C     = (const float*)d_in[1];
    const float* G     = (const float*)d_in[2];
    const float* W     = (const float*)d_in[3];
    const float* b     = (const float*)d_in[4];
    const float* sigma = (const float*)d_in[5];
    const float* rho   = (const float*)d_in[6];
    float* wsF = (float*)d_ws;
    float* out = (float*)d_out;

    hipLaunchKernelGGL(mega_kernel, dim3(96), dim3(256), 0, stream,
                       X, C, G, W, b, sigma, rho, wsF);
    hipLaunchKernelGGL(finalize_kernel, dim3(1), dim3(512), 0, stream,
                       sigma, rho, wsF, out);
}

// Round 5
// 102.000 us; speedup vs baseline: 1.0459x; 1.0459x over previous
//
#include <hip/hip_runtime.h>
#include <math.h>

#define NV 512
#define KC 32
#define NB 192
#define LOG2PI 1.8378770664093453f

typedef __attribute__((ext_vector_type(8))) short short8;
typedef __attribute__((ext_vector_type(4))) float float4v;
typedef __attribute__((ext_vector_type(4))) int int4v;

// ws layout (floats) — all per-block EXCLUSIVE slices, fully overwritten
// every launch (0xAA poison harmless). Layouts chosen so the single-block
// finalize reads are lane-consecutive (coalesced):
//   WS_PM : P[8][12][16][32]  (i_slice, b_tile, row, col)      49152
//   WS_VP : Vp[12][8][64]     (b_tile, i_slice, col-local)      6144
//   WS_MM9: Mp[96]                                                96
//   WS_ST : 12 stat slices x 580: [u 512][sx1 32][sx2 32][xx 1] 6960
//   WS_P  : [coef 32][logdet 1]
#define WS_PM  0
#define WS_VP  49152
#define WS_MM9 55296
#define WS_ST  55392
#define ST_STRIDE 580
#define WS_P   62352

// pack two fp32 (bit patterns) into two bf16 (round-half-up)
static __device__ inline uint pkbf(uint lo, uint hi) {
    return ((hi + 0x8000u) & 0xffff0000u) | ((lo + 0x8000u) >> 16);
}

__global__ __launch_bounds__(256) void mega_kernel(
    const float* __restrict__ X, const float* __restrict__ C,
    const float* __restrict__ G, const float* __restrict__ W,
    const float* __restrict__ bias, const float* __restrict__ sigma,
    const float* __restrict__ rho, float* __restrict__ wsF)
{
    const int bid = blockIdx.x, tid = threadIdx.x;
    const int blk_b = bid >> 3, blk_i = bid & 7;   // 12 b-tiles x 8 i-tiles
    const int b0 = blk_b * 16, i0blk = blk_i * 64;
    const int w = tid >> 6, lane = tid & 63;
    const int m = lane & 15, q = lane >> 4;
    const int i0w = i0blk + w * 16;
    const int q8 = q * 8;

    __shared__ int asg[NV];
    __shared__ float Gs[KC * KC];
    __shared__ uint Gbits[KC];
    __shared__ unsigned long long kmask[KC][8];  // [c1][g]: bit j = G[c1][asg[g*64+j]]
    __shared__ float smL[16 * KC];
    __shared__ float varr[64];
    __shared__ float mmred[4];
    __shared__ float smrows[16][KC];
    __shared__ int cnt[KC];
    __shared__ float ldred[KC];

    // ---- cluster assignment from one-hot C (exact 0/1), float4 loads
    {
        const int n0 = tid * 2;
        #pragma unroll
        for (int h = 0; h < 2; ++h) {
            const int n = n0 + h;
            const float* row = C + n * KC;
            float a = 0.f;
            #pragma unroll
            for (int c4 = 0; c4 < 8; ++c4) {
                const float4 f = *(const float4*)(row + c4 * 4);
                a += f.x * (float)(c4 * 4) + f.y * (float)(c4 * 4 + 1)
                   + f.z * (float)(c4 * 4 + 2) + f.w * (float)(c4 * 4 + 3);
            }
            asg[n] = (int)(a + 0.5f);
        }
    }
    for (int l = tid; l < KC * KC; l += 256) Gs[l] = G[l];
    for (int l = tid; l < 16 * KC; l += 256) smL[l] = 0.f;
    if (tid < 64) varr[tid] = 0.f;
    __syncthreads();
    if (tid < KC) {
        uint bits = 0;
        #pragma unroll
        for (int c2 = 0; c2 < KC; ++c2)
            bits |= (Gs[tid * KC + c2] > 0.5f ? 1u : 0u) << c2;
        Gbits[tid] = bits;
    }
    __syncthreads();
    // ---- kmask via ballot: wave w covers k-groups 2w, 2w+1
    #pragma unroll
    for (int gi = 0; gi < 2; ++gi) {
        const int g = w * 2 + gi;
        const int a = asg[g * 64 + lane];
        #pragma unroll
        for (int c1 = 0; c1 < KC; ++c1) {
            const unsigned long long bm = __ballot((Gbits[c1] >> a) & 1u);
            if (lane == c1) kmask[c1][g] = bm;
        }
    }
    __syncthreads();

    // ---- per-thread mask: 16 chunks x 8 bits packed into 4 uints
    const int carow = asg[i0w + m];
    const uint* kmrow = (const uint*)&kmask[carow][0];   // uint s = k-bits [s*32,+32)
    uint m4[4];
    #pragma unroll
    for (int j = 0; j < 4; ++j) {
        m4[j] =  ((kmrow[4 * j]     >> q8) & 0xffu)
              | (((kmrow[4 * j + 1] >> q8) & 0xffu) << 8)
              | (((kmrow[4 * j + 2] >> q8) & 0xffu) << 16)
              | (((kmrow[4 * j + 3] >> q8) & 0xffu) << 24);
    }

    // ---- MFMA GEMM, fp32 loads + in-register bf16 convert + mask
    const float* aRow = X + (b0 + m) * NV;
    const float* bRow = W + (i0w + m) * NV;
    float4v acc = {0.f, 0.f, 0.f, 0.f};
    #pragma unroll 4
    for (int s = 0; s < 16; ++s) {
        const int k0 = q8 + s * 32;
        const float4 a0 = *(const float4*)(aRow + k0);
        const float4 a1 = *(const float4*)(aRow + k0 + 4);
        const float4 w0 = *(const float4*)(bRow + k0);
        const float4 w1 = *(const float4*)(bRow + k0 + 4);
        const uint bits = (m4[s >> 2] >> ((s & 3) * 8)) & 0xffu;
        const uint b0u = (bits & 1u)   ? __float_as_uint(w0.x) : 0u;
        const uint b1u = (bits & 2u)   ? __float_as_uint(w0.y) : 0u;
        const uint b2u = (bits & 4u)   ? __float_as_uint(w0.z) : 0u;
        const uint b3u = (bits & 8u)   ? __float_as_uint(w0.w) : 0u;
        const uint b4u = (bits & 16u)  ? __float_as_uint(w1.x) : 0u;
        const uint b5u = (bits & 32u)  ? __float_as_uint(w1.y) : 0u;
        const uint b6u = (bits & 64u)  ? __float_as_uint(w1.z) : 0u;
        const uint b7u = (bits & 128u) ? __float_as_uint(w1.w) : 0u;
        int4v ai, bi;
        ai.x = (int)pkbf(__float_as_uint(a0.x), __float_as_uint(a0.y));
        ai.y = (int)pkbf(__float_as_uint(a0.z), __float_as_uint(a0.w));
        ai.z = (int)pkbf(__float_as_uint(a1.x), __float_as_uint(a1.y));
        ai.w = (int)pkbf(__float_as_uint(a1.z), __float_as_uint(a1.w));
        bi.x = (int)pkbf(b0u, b1u);
        bi.y = (int)pkbf(b2u, b3u);
        bi.z = (int)pkbf(b4u, b5u);
        bi.w = (int)pkbf(b6u, b7u);
        acc = __builtin_amdgcn_mfma_f32_16x16x32_bf16(
            __builtin_bit_cast(short8, ai), __builtin_bit_cast(short8, bi), acc, 0, 0, 0);
    }

    // ---- epilogue: C/D layout col=lane&15, row=q*4+reg (m89-verified)
    {
        const float bv = bias[i0w + m];
        float vsum = 0.f, mml = 0.f;
        #pragma unroll
        for (int r = 0; r < 4; ++r) {
            const float val = acc[r] + bv;
            vsum += val; mml += val * val;
            atomicAdd(&smL[(q * 4 + r) * KC + carow], val);
        }
        atomicAdd(&varr[w * 16 + m], vsum);
        for (int off = 32; off; off >>= 1) mml += __shfl_down(mml, off, 64);
        if (lane == 0) mmred[w] = mml;
    }
    __syncthreads();
    {
        float* pdst = wsF + WS_PM + (blk_i * 12 + blk_b) * 512;
        for (int l = tid; l < 512; l += 256) pdst[l] = smL[l];
        if (tid < 64) wsF[WS_VP + (blk_b * 8 + blk_i) * 64 + tid] = varr[tid];
        if (tid == 0) wsF[WS_MM9 + bid] = mmred[0] + mmred[1] + mmred[2] + mmred[3];
    }

    // ---- X stats (exact fp32) in blk_i==0 blocks, rows [b0, b0+16)
    if (blk_i == 0) {
        __syncthreads();
        for (int l = tid; l < 16 * KC; l += 256) ((float*)smrows)[l] = 0.f;
        __syncthreads();
        const int c0 = tid * 2;
        const int ca = asg[c0], cb = asg[c0 + 1];
        float u0 = 0.f, u1 = 0.f, xx = 0.f;
        #pragma unroll
        for (int r = 0; r < 16; ++r) {
            const float2 xv = *(const float2*)(X + (b0 + r) * NV + c0);
            u0 += xv.x; u1 += xv.y;
            xx += xv.x * xv.x + xv.y * xv.y;
            atomicAdd(&smrows[r][ca], xv.x);
            atomicAdd(&smrows[r][cb], xv.y);
        }
        for (int off = 32; off; off >>= 1) xx += __shfl_down(xx, off, 64);
        if ((tid & 63) == 0) mmred[tid >> 6] = xx;
        __syncthreads();
        float* st = wsF + WS_ST + blk_b * ST_STRIDE;
        st[c0] = u0; st[c0 + 1] = u1;
        if (tid < KC) {
            float s1 = 0.f, s2 = 0.f;
            #pragma unroll
            for (int r = 0; r < 16; ++r) { const float s = smrows[r][tid]; s1 += s; s2 += s * s; }
            st[512 + tid] = s1;
            st[544 + tid] = s2;
        }
        if (tid == 0) st[576] = mmred[0] + mmred[1] + mmred[2] + mmred[3];
    }

    // ---- coef/logdet in block 0
    if (bid == 0) {
        if (tid < KC) cnt[tid] = 0;
        __syncthreads();
        for (int n = tid; n < NV; n += 256) atomicAdd(&cnt[asg[n]], 1);
        __syncthreads();
        const float s2v = sigma[0] * sigma[0], rh = rho[0];
        const float av = s2v * (1.f - rh), bvv = s2v * rh;
        if (tid < KC) {
            const int nc = cnt[tid];
            wsF[WS_P + tid] = bvv / (av * (av + bvv * (float)nc));
            ldred[tid] = (float)(nc - 1) * logf(av) + logf(av + bvv * (float)nc);
        }
        __syncthreads();
        if (tid == 0) {
            float ld = 0.f;
            for (int c = 0; c < KC; ++c) ld += ldred[c];
            wsF[WS_P + 32] = ld;
        }
    }
}

__global__ __launch_bounds__(512) void finalize_kernel(
    const float* __restrict__ sigma, const float* __restrict__ rho,
    const float* __restrict__ wsF, float* __restrict__ out)
{
    const int tid = threadIdx.x;
    __shared__ float SM1s[KC], SM2s[KC];
    __shared__ float accs[4];   // 0:MM 1:XX 2:cross(u.v) 3:Q
    if (tid < KC) { SM1s[tid] = 0.f; SM2s[tid] = 0.f; }
    if (tid < 4) accs[tid] = 0.f;
    __syncthreads();
    const float* st = wsF + WS_ST;

    // SM1/SM2: thread (c = tid&31, g = tid>>5): rows b = j*16+g, coalesced in c
    {
        const int c = tid & 31, g = tid >> 5;
        float s1 = 0.f, s2 = 0.f;
        #pragma unroll
        for (int j = 0; j < 12; ++j) {
            float s = 0.f;
            #pragma unroll
            for (int ib = 0; ib < 8; ++ib)
                s += wsF[WS_PM + (ib * 12 + j) * 512 + g * 32 + c];
            s1 += s; s2 += s * s;
        }
        atomicAdd(&SM1s[c], s1);
        atomicAdd(&SM2s[c], s2);
    }
    // u, v, cross (tid == column i), coalesced
    {
        float v = 0.f, u = 0.f;
        #pragma unroll
        for (int bb = 0; bb < 12; ++bb)
            v += wsF[WS_VP + (bb * 8 + (tid >> 6)) * 64 + (tid & 63)];
        #pragma unroll
        for (int sb = 0; sb < 12; ++sb) u += st[sb * ST_STRIDE + tid];
        float cr = u * v;
        for (int off = 32; off; off >>= 1) cr += __shfl_down(cr, off, 64);
        if ((tid & 63) == 0) atomicAdd(&accs[2], cr);
    }
    // MM
    {
        float mm = (tid < 96) ? wsF[WS_MM9 + tid] : 0.f;
        for (int off = 32; off; off >>= 1) mm += __shfl_down(mm, off, 64);
        if ((tid & 63) == 0) atomicAdd(&accs[0], mm);
    }
    // XX
    {
        float xx = (tid < 12) ? st[tid * ST_STRIDE + 576] : 0.f;
        for (int off = 32; off; off >>= 1) xx += __shfl_down(xx, off, 64);
        if ((tid & 63) == 0) atomicAdd(&accs[1], xx);
    }
    __syncthreads();
    // Q term
    {
        float qv = 0.f;
        if (tid < KC) {
            float s1 = 0.f, s2 = 0.f;
            #pragma unroll
            for (int sb = 0; sb < 12; ++sb) {
                s1 += st[sb * ST_STRIDE + 512 + tid];
                s2 += st[sb * ST_STRIDE + 544 + tid];
            }
            const float coef = wsF[WS_P + tid];
            qv = coef * (s2 * (1.f / NB) + SM2s[tid] * (1.f / NB)
                         - 2.f * s1 * SM1s[tid] * (1.f / ((float)NB * (float)NB)));
        }
        for (int off = 32; off; off >>= 1) qv += __shfl_down(qv, off, 64);
        if (tid == 0) atomicAdd(&accs[3], qv);
    }
    __syncthreads();
    if (tid == 0) {
        const float s2v = sigma[0] * sigma[0], rh = rho[0];
        const float av = s2v * (1.f - rh);
        const float meanD2 = accs[1] * (1.f / NB) + accs[0] * (1.f / NB)
                           - 2.f * accs[2] / ((float)NB * (float)NB);
        const float maha = meanD2 / av - accs[3];
        out[0] = -0.5f * (maha + wsF[WS_P + 32] + (float)NV * LOG2PI);
    }
}

extern "C" void kernel_launch(void* const* d_in, const int* in_sizes, int n_in,
                              void* d_out, int out_size, void* d_ws, size_t ws_size,
                              hipStream_t stream) {
    const float* X     = (const float*)d_in[0];
    const float* C     = (const float*)d_in[1];
    const float* G     = (const float*)d_in[2];
    const float* W     = (const float*)d_in[3];
    const float* b     = (const float*)d_in[4];
    const float* sigma = (const float*)d_in[5];
    const float* rho   = (const float*)d_in[6];
    float* wsF = (float*)d_ws;
    float* out = (float*)d_out;

    hipLaunchKernelGGL(mega_kernel, dim3(96), dim3(256), 0, stream,
                       X, C, G, W, b, sigma, rho, wsF);
    hipLaunchKernelGGL(finalize_kernel, dim3(1), dim3(512), 0, stream,
                       sigma, rho, wsF, out);
}

// Round 6
// 86.361 us; speedup vs baseline: 1.2353x; 1.1811x over previous
//
#include <hip/hip_runtime.h>
#include <math.h>

#define NV 512
#define KC 32
#define NB 192
#define LOG2PI 1.8378770664093453f

typedef __attribute__((ext_vector_type(8))) short short8;
typedef __attribute__((ext_vector_type(4))) float float4v;

// ws layout (float units):
#define WS_SM    0        // sm[192*32]: zeroed by prep (node1), atomic-accum by gemm (node2)
#define WS_GV    6144     // 96 slices x 65: [v 64][mm 1]
#define WS_STATS 12400    // 24 slices x 608: [u 512][sx1 32][sx2 32][xx 1]
#define WS_P     27000    // [coef 32][logdet 1]
#define WS_ASG   27040    // int asg[512]
#define WS_CNT   27552    // int completion counter (zeroed by prep)
#define WS_XBF   27556    // bf16 X [192*512]  (16B-aligned: 27556*4 % 16 == 0)
#define WS_WBF   76708    // bf16 Wm [512*512] (16B-aligned)

static __device__ inline ushort f2bf(float f) {
    uint u = __float_as_uint(f);
    uint r = (u + 0x7fffu + ((u >> 16) & 1u)) >> 16;   // RNE
    return (ushort)r;
}

// ---------------- node 1: convert + stats + prep ----------------
__global__ __launch_bounds__(256) void prep_kernel(
    const float* __restrict__ X, const float* __restrict__ C,
    const float* __restrict__ G, const float* __restrict__ W,
    const float* __restrict__ bias, const float* __restrict__ sigma,
    const float* __restrict__ rho, float* __restrict__ wsF, int* __restrict__ wsI)
{
    const int bid = blockIdx.x, tid = threadIdx.x;
    __shared__ int asg[NV];
    __shared__ float Gs[KC * KC];
    __shared__ float smrows[8][KC];
    __shared__ float redw[4];

    // cluster assignment from one-hot C (exact 0/1 values)
    for (int n = tid; n < NV; n += 256) {
        const float* row = C + n * KC;
        float a = 0.f;
        #pragma unroll
        for (int c2 = 0; c2 < KC; ++c2) a += row[c2] * (float)c2;
        asg[n] = (int)(a + 0.5f);
    }

    if (bid < 24) {
        // ---- convert X rows [bid*8, +8) to bf16
        __syncthreads();
        ushort* xbf = (ushort*)(wsF + WS_XBF);
        const int base = bid * 8 * NV;
        #pragma unroll
        for (int p = 0; p < 4; ++p) {
            const int off = base + tid * 4 + p * 1024;
            const float4 f = *(const float4*)(X + off);
            ushort4 o;
            o.x = f2bf(f.x); o.y = f2bf(f.y); o.z = f2bf(f.z); o.w = f2bf(f.w);
            *(ushort4*)(xbf + off) = o;
        }
    } else if (bid < 88) {
        // ---- convert masked W rows [(bid-24)*8, +8) to bf16
        for (int l = tid; l < KC * KC; l += 256) Gs[l] = G[l];
        __syncthreads();
        ushort* wbf = (ushort*)(wsF + WS_WBF);
        const int i0 = (bid - 24) * 8;
        #pragma unroll
        for (int p = 0; p < 4; ++p) {
            const int l = tid * 4 + p * 1024;          // 0..4095 strip-local
            const int ir = i0 + (l >> 9), k = l & 511;
            const float* grow = Gs + asg[ir] * KC;
            const float4 f = *(const float4*)(W + ir * NV + k);
            ushort4 o;
            o.x = f2bf(f.x * grow[asg[k]]);
            o.y = f2bf(f.y * grow[asg[k + 1]]);
            o.z = f2bf(f.z * grow[asg[k + 2]]);
            o.w = f2bf(f.w * grow[asg[k + 3]]);
            *(ushort4*)(wbf + ir * NV + k) = o;
        }
    } else if (bid < 112) {
        // ---- X stats: 8 rows -> u partials, xx, per-row cluster sums -> sx1/sx2
        for (int l = tid; l < 8 * KC; l += 256) ((float*)smrows)[l] = 0.f;
        if (tid < 4) redw[tid] = 0.f;
        __syncthreads();
        const int sb = bid - 88, row0 = sb * 8;
        const int c0 = tid * 2;
        const int ca = asg[c0], cb = asg[c0 + 1];
        float u0 = 0.f, u1 = 0.f, xx = 0.f;
        #pragma unroll
        for (int r = 0; r < 8; ++r) {
            const float2 xv = *(const float2*)(X + (row0 + r) * NV + c0);
            u0 += xv.x; u1 += xv.y;
            xx += xv.x * xv.x + xv.y * xv.y;
            atomicAdd(&smrows[r][ca], xv.x);
            atomicAdd(&smrows[r][cb], xv.y);
        }
        for (int off = 32; off; off >>= 1) xx += __shfl_down(xx, off, 64);
        if ((tid & 63) == 0) redw[tid >> 6] = xx;
        __syncthreads();
        float* slice = wsF + WS_STATS + sb * 608;
        slice[c0] = u0; slice[c0 + 1] = u1;
        if (tid < KC) {
            float s1 = 0.f, s2 = 0.f;
            #pragma unroll
            for (int r = 0; r < 8; ++r) { const float s = smrows[r][tid]; s1 += s; s2 += s * s; }
            slice[512 + tid] = s1;
            slice[544 + tid] = s2;
        }
        if (tid == 0) slice[576] = redw[0] + redw[1] + redw[2] + redw[3];
    } else {
        // ---- prep: counts -> coef/logdet, persist asg, zero sm + counter
        __shared__ int cnt[KC];
        __shared__ float ldred[KC];
        if (tid < KC) cnt[tid] = 0;
        __syncthreads();
        for (int n = tid; n < NV; n += 256) {
            atomicAdd(&cnt[asg[n]], 1);
            wsI[WS_ASG + n] = asg[n];
        }
        for (int l = tid; l < NB * KC; l += 256) wsF[WS_SM + l] = 0.f;
        if (tid == 0) wsI[WS_CNT] = 0;
        __syncthreads();
        const float s2v = sigma[0] * sigma[0];
        const float rh = rho[0];
        const float av = s2v * (1.f - rh), bv = s2v * rh;
        if (tid < KC) {
            const int nc = cnt[tid];
            wsF[WS_P + tid] = bv / (av * (av + bv * (float)nc));
            ldred[tid] = (float)(nc - 1) * logf(av) + logf(av + bv * (float)nc);
        }
        __syncthreads();
        if (tid == 0) {
            float ld = 0.f;
            for (int c2 = 0; c2 < KC; ++c2) ld += ldred[c2];
            wsF[WS_P + 32] = ld;
        }
    }
}

// ---------------- node 2: MFMA GEMM + last-block finalize ----------------
__global__ __launch_bounds__(256) void gemm_kernel(
    const float* __restrict__ bias, const float* __restrict__ sigma,
    const float* __restrict__ rho, float* __restrict__ wsF,
    int* __restrict__ wsI, float* __restrict__ out)
{
    const int bid = blockIdx.x, tid = threadIdx.x;
    const int blk_b = bid >> 3, blk_i = bid & 7;     // 12 b-tiles x 8 i-tiles
    const int b0 = blk_b * 16, i0blk = blk_i * 64;
    const int w = tid >> 6, lane = tid & 63;
    const int m = lane & 15, q = lane >> 4;
    const int i0w = i0blk + w * 16;

    __shared__ float smL[16 * KC];
    __shared__ float varr[64];
    __shared__ int asgc[64];
    __shared__ float mmred[4];
    __shared__ int isLast;
    for (int l = tid; l < 16 * KC; l += 256) smL[l] = 0.f;
    if (tid < 64) { varr[tid] = 0.f; asgc[tid] = wsI[WS_ASG + i0blk + tid]; }
    if (tid < 4) mmred[tid] = 0.f;

    const ushort* xbf = (const ushort*)(wsF + WS_XBF);
    const ushort* wbf = (const ushort*)(wsF + WS_WBF);
    const short8* ap = (const short8*)(xbf + (b0 + m) * NV + q * 8);
    const short8* bp = (const short8*)(wbf + (i0w + m) * NV + q * 8);
    float4v acc = {0.f, 0.f, 0.f, 0.f};
    #pragma unroll
    for (int s = 0; s < 16; ++s) {
        const short8 a = ap[s * 4];     // s*32 shorts = 4 short8
        const short8 b = bp[s * 4];
        acc = __builtin_amdgcn_mfma_f32_16x16x32_bf16(a, b, acc, 0, 0, 0);
    }
    __syncthreads();

    // epilogue: C/D layout col=lane&15, row=q*4+reg (m89-verified)
    const int col = i0w + m;
    const float bv = bias[col];
    const int ca = asgc[w * 16 + m];
    float vsum = 0.f, mml = 0.f;
    #pragma unroll
    for (int r = 0; r < 4; ++r) {
        const float val = acc[r] + bv;
        vsum += val; mml += val * val;
        atomicAdd(&smL[(q * 4 + r) * KC + ca], val);
    }
    atomicAdd(&varr[w * 16 + m], vsum);
    for (int off = 32; off; off >>= 1) mml += __shfl_down(mml, off, 64);
    if (lane == 0) mmred[w] = mml;
    __syncthreads();

    float* smG = wsF + WS_SM;
    for (int l = tid; l < 16 * KC; l += 256)
        atomicAdd(&smG[(b0 + (l >> 5)) * KC + (l & 31)], smL[l]);
    float* slice = wsF + WS_GV + bid * 65;
    if (tid < 64) slice[tid] = varr[tid];
    if (tid == 0) slice[64] = mmred[0] + mmred[1] + mmred[2] + mmred[3];

    // ---- completion protocol: release writes, bump counter, last block finalizes
    __syncthreads();                 // all block stores/atomics drained (vmcnt 0)
    if (tid == 0) {
        __threadfence();             // agent-scope release: L2 writeback
        const int old = atomicAdd(&wsI[WS_CNT], 1);
        isLast = (old == 95);
    }
    __syncthreads();
    if (!isLast) return;
    if (tid == 0) __threadfence();   // acquire: invalidate stale lines before reads
    __syncthreads();

    // ---- finalize (R3 body): reads sm (atomics), gv slices, stats, coef
    __shared__ float SM1s[KC], SM2s[KC];
    __shared__ float accs[4];        // 0:MM 1:XX 2:cross(u.v) 3:Q
    if (tid < KC) { SM1s[tid] = 0.f; SM2s[tid] = 0.f; }
    if (tid < 4) accs[tid] = 0.f;
    __syncthreads();
    const float* sm = wsF + WS_SM;
    const float* gv = wsF + WS_GV;
    const float* st = wsF + WS_STATS;

    {   // SM1/SM2 over sm[192][32], coalesced in c
        const int c = tid & 31, r0 = tid >> 5;
        float s1 = 0.f, s2 = 0.f;
        #pragma unroll
        for (int j = 0; j < 24; ++j) {
            const float s = sm[(r0 + 8 * j) * KC + c];
            s1 += s; s2 += s * s;
        }
        atomicAdd(&SM1s[c], s1);
        atomicAdd(&SM2s[c], s2);
    }
    {   // u, v, cross term (2 cols per thread)
        float cr = 0.f;
        #pragma unroll
        for (int h = 0; h < 2; ++h) {
            const int i = tid + h * 256;
            float u = 0.f;
            #pragma unroll
            for (int sb = 0; sb < 24; ++sb) u += st[sb * 608 + i];
            float v = 0.f;
            const int bi2 = i >> 6, loc = i & 63;
            #pragma unroll
            for (int bb = 0; bb < 12; ++bb) v += gv[(bb * 8 + bi2) * 65 + loc];
            cr += u * v;
        }
        for (int off = 32; off; off >>= 1) cr += __shfl_down(cr, off, 64);
        if ((tid & 63) == 0) atomicAdd(&accs[2], cr);
    }
    {   // MM
        float mm = (tid < 96) ? gv[tid * 65 + 64] : 0.f;
        for (int off = 32; off; off >>= 1) mm += __shfl_down(mm, off, 64);
        if ((tid & 63) == 0) atomicAdd(&accs[0], mm);
    }
    {   // XX
        float xx = (tid < 24) ? st[tid * 608 + 576] : 0.f;
        for (int off = 32; off; off >>= 1) xx += __shfl_down(xx, off, 64);
        if ((tid & 63) == 0) atomicAdd(&accs[1], xx);
    }
    __syncthreads();
    {   // Q term
        float qv = 0.f;
        if (tid < KC) {
            float s1 = 0.f, s2 = 0.f;
            #pragma unroll
            for (int sb = 0; sb < 24; ++sb) {
                s1 += st[sb * 608 + 512 + tid];
                s2 += st[sb * 608 + 544 + tid];
            }
            const float coef = wsF[WS_P + tid];
            qv = coef * (s2 * (1.f / NB) + SM2s[tid] * (1.f / NB)
                         - 2.f * s1 * SM1s[tid] * (1.f / ((float)NB * (float)NB)));
        }
        for (int off = 32; off; off >>= 1) qv += __shfl_down(qv, off, 64);
        if (tid == 0) atomicAdd(&accs[3], qv);
    }
    __syncthreads();
    if (tid == 0) {
        const float s2v = sigma[0] * sigma[0];
        const float rh = rho[0];
        const float av = s2v * (1.f - rh);
        const float meanD2 = accs[1] * (1.f / NB) + accs[0] * (1.f / NB)
                           - 2.f * accs[2] / ((float)NB * (float)NB);
        const float maha = meanD2 / av - accs[3];
        out[0] = -0.5f * (maha + wsF[WS_P + 32] + (float)NV * LOG2PI);
    }
}

extern "C" void kernel_launch(void* const* d_in, const int* in_sizes, int n_in,
                              void* d_out, int out_size, void* d_ws, size_t ws_size,
                              hipStream_t stream) {
    const float* X     = (const float*)d_in[0];
    const float* C     = (const float*)d_in[1];
    const float* G     = (const float*)d_in[2];
    const float* W     = (const float*)d_in[3];
    const float* b     = (const float*)d_in[4];
    const float* sigma = (const float*)d_in[5];
    const float* rho   = (const float*)d_in[6];
    float* wsF = (float*)d_ws;
    int*   wsI = (int*)d_ws;
    float* out = (float*)d_out;

    hipLaunchKernelGGL(prep_kernel, dim3(113), dim3(256), 0, stream,
                       X, C, G, W, b, sigma, rho, wsF, wsI);
    hipLaunchKernelGGL(gemm_kernel, dim3(96), dim3(256), 0, stream,
                       b, sigma, rho, wsF, wsI, out);
}